// Round 14
// baseline (253.079 us; speedup 1.0000x reference)
//
#include <hip/hip_runtime.h>
#include <hip/hip_bf16.h>
#include <hip/hip_fp16.h>

#define N_NODES 10000
#define N_EDGES 80000
#define FN 16
#define FE 8
#define HID 25
#define C1 32
#define C2 64
#define NU_BLOCKS 256
#define FC_BLOCKS 640
#define HROW 28   // padded h row in halfs: [25 vals][1.0][0][0] -> 56B, 8B-aligned
#define SLOTS 40  // bucket capacity; Poisson(8) => P(deg>=40) ~ 5e-16
#define SC_BLOCKS ((N_EDGES + 255) / 256)  // 313

typedef _Float16 h16;
typedef _Float16 h16x4 __attribute__((ext_vector_type(4)));

__device__ __forceinline__ float elu_f(float x) { return x > 0.f ? x : (expf(x) - 1.f); }

// dot of one padded h row (28 halfs, 7x8B vector loads) against Pk[28]
__device__ __forceinline__ float hdot(const h16* __restrict__ row, const float* Pk) {
    const h16x4* rv = (const h16x4*)row;
    float s = 0.f;
#pragma unroll
    for (int q = 0; q < 7; q++) {
        h16x4 hv = rv[q];
        s += (float)hv.x * Pk[4 * q] + (float)hv.y * Pk[4 * q + 1] +
             (float)hv.z * Pk[4 * q + 2] + (float)hv.w * Pk[4 * q + 3];
    }
    return s;
}

// --- m-major precompute (fp16 out): P[n,k*COUT+o] = sum_i x[n,i]*w2[k,i,o];
//     row k==HID is the b2 term. One w2 column per thread, reused for 50 nodes. ---
template <int CIN, int COUT>
__device__ __forceinline__ void pre_block(const float* __restrict__ xin,
                                          const float* __restrict__ w2,
                                          const float* __restrict__ b2,
                                          h16* __restrict__ P, int u, int tid) {
    constexpr int M = (HID + 1) * COUT;
    constexpr int MB = (M + 255) / 256;
    constexpr int TN = 50;
    int mb = u % MB;
    int n0 = (u / MB) * TN;
    int m = mb * 256 + tid;
    if (m >= M) return;
    int k = m / COUT, o = m % COUT;
    float wreg[CIN];
    if (k < HID) {
#pragma unroll
        for (int i = 0; i < CIN; i++) wreg[i] = w2[(size_t)(k * CIN + i) * COUT + o];
    } else {
#pragma unroll
        for (int i = 0; i < CIN; i++) wreg[i] = b2[i * COUT + o];
    }
    for (int n = n0; n < n0 + TN; n++) {
        const float* xr = xin + (size_t)n * CIN;  // wave-uniform -> s_load
        float s = 0.f;
#pragma unroll
        for (int i = 0; i < CIN; i++) s += xr[i] * wreg[i];
        P[(size_t)n * M + m] = (h16)s;
    }
}

// --- K1: blocks [0,SC_BLOCKS): bucket-scatter + edge-MLP hidden (padded fp16
//         rows via vector stores) + dst degree. blocks beyond: precompute P1. ---
__global__ void k_scatter_pre1(const float* __restrict__ ea, const int* __restrict__ ei,
                               const float* __restrict__ w1a, const float* __restrict__ b1a,
                               const float* __restrict__ w1b, const float* __restrict__ b1b,
                               const float* __restrict__ x, const float* __restrict__ w2a,
                               const float* __restrict__ b2a,
                               int* __restrict__ cnt_src, int* __restrict__ cnt_dst,
                               int* __restrict__ ebuf, h16* __restrict__ h1r,
                               h16* __restrict__ h2r, h16* __restrict__ P1) {
    int tid = threadIdx.x;
    int bid = blockIdx.x;
    if (bid >= SC_BLOCKS) {
        pre_block<FN, C1>(x, w2a, b2a, P1, bid - SC_BLOCKS, tid);
        return;
    }
    __shared__ float sw1a[FE * HID], sw1b[FE * HID], sb1a[HID], sb1b[HID];
    for (int i = tid; i < FE * HID; i += 256) { sw1a[i] = w1a[i]; sw1b[i] = w1b[i]; }
    if (tid < HID) { sb1a[tid] = b1a[tid]; sb1b[tid] = b1b[tid]; }
    __syncthreads();
    int e = bid * 256 + tid;
    if (e >= N_EDGES) return;
    float a[FE];
#pragma unroll
    for (int i = 0; i < FE; i++) a[i] = ea[e * FE + i];
    int src = ei[e], dst = ei[N_EDGES + e];
    int slot = atomicAdd(&cnt_src[src], 1);
    int pos = src * SLOTS + slot;
    ebuf[pos] = dst;
    atomicAdd(&cnt_dst[dst], 1);
    h16 b1buf[HROW], b2buf[HROW];
#pragma unroll
    for (int k = 0; k < HID; k++) {
        float s1 = sb1a[k], s2 = sb1b[k];
#pragma unroll
        for (int i = 0; i < FE; i++) { s1 += a[i] * sw1a[i * HID + k]; s2 += a[i] * sw1b[i * HID + k]; }
        b1buf[k] = (h16)fmaxf(s1, 0.f);
        b2buf[k] = (h16)fmaxf(s2, 0.f);
    }
    // pad: [25]=1 (picks up b2 term in the flat dot), [26]=[27]=0
    b1buf[25] = (h16)1.f; b1buf[26] = (h16)0.f; b1buf[27] = (h16)0.f;
    b2buf[25] = (h16)1.f; b2buf[26] = (h16)0.f; b2buf[27] = (h16)0.f;
    h16x4* h1p = (h16x4*)(h1r + (size_t)pos * HROW);
    h16x4* h2p = (h16x4*)(h2r + (size_t)pos * HROW);
#pragma unroll
    for (int q = 0; q < 7; q++) {
        h1p[q] = ((const h16x4*)b1buf)[q];
        h2p[q] = ((const h16x4*)b2buf)[q];
    }
}

// --- K5: conv2 precompute (standalone) ---
template <int CIN, int COUT>
__global__ void k_precompute(const float* __restrict__ xin, const float* __restrict__ w2,
                             const float* __restrict__ b2, h16* __restrict__ P) {
    pre_block<CIN, COUT>(xin, w2, b2, P, blockIdx.x, threadIdx.x);
}

// --- K2: conv1 message. Wave per node; paired edges in half-waves; 2-pair (4-edge)
//         unroll; padded-row flat dot (7 vector loads/edge). ---
__global__ void k_msg_c1(const h16* __restrict__ P, const int* __restrict__ cnt_src,
                         const int* __restrict__ ebuf, const h16* __restrict__ h1r,
                         float* __restrict__ agg) {
    constexpr int M = (HID + 1) * C1;
    int lane = threadIdx.x & 63;
    int o = lane & 31;
    int n = __builtin_amdgcn_readfirstlane(blockIdx.x * 4 + (threadIdx.x >> 6));
    if (n >= N_NODES) return;
    const h16* Pr = P + (size_t)n * M;
    float Pk[HROW];
#pragma unroll
    for (int k = 0; k <= HID; k++) Pk[k] = (float)Pr[k * C1 + o];
    Pk[26] = 0.f; Pk[27] = 0.f;
    int beg = n * SLOTS, end = beg + cnt_src[n];
    int idx = beg;
    for (; idx + 3 < end; idx += 4) {
        int d0 = ebuf[idx], d1 = ebuf[idx + 1], d2 = ebuf[idx + 2], d3 = ebuf[idx + 3];
        float s0 = hdot(h1r + (size_t)idx * HROW, Pk);
        float s1 = hdot(h1r + (size_t)(idx + 1) * HROW, Pk);
        float s2 = hdot(h1r + (size_t)(idx + 2) * HROW, Pk);
        float s3 = hdot(h1r + (size_t)(idx + 3) * HROW, Pk);
        float va = (lane < 32) ? s0 : s1;
        int da = (lane < 32) ? d0 : d1;
        atomicAdd(&agg[da * C1 + o], va);
        float vb = (lane < 32) ? s2 : s3;
        int db = (lane < 32) ? d2 : d3;
        atomicAdd(&agg[db * C1 + o], vb);
    }
    for (; idx + 1 < end; idx += 2) {
        int d0 = ebuf[idx], d1 = ebuf[idx + 1];
        float s0 = hdot(h1r + (size_t)idx * HROW, Pk);
        float s1 = hdot(h1r + (size_t)(idx + 1) * HROW, Pk);
        float va = (lane < 32) ? s0 : s1;
        int da = (lane < 32) ? d0 : d1;
        atomicAdd(&agg[da * C1 + o], va);
    }
    if (idx < end) {
        int d0 = ebuf[idx];
        float s0 = hdot(h1r + (size_t)idx * HROW, Pk);
        if (lane < 32) atomicAdd(&agg[d0 * C1 + o], s0);
    }
}

// --- K6: conv2 message. Wave per node; lane = channel; 4-edge unroll; padded-row
//         flat dot. ---
__global__ void k_msg_c2(const h16* __restrict__ P, const int* __restrict__ cnt_src,
                         const int* __restrict__ ebuf, const h16* __restrict__ h2r,
                         float* __restrict__ agg) {
    constexpr int M = (HID + 1) * C2;
    int lane = threadIdx.x & 63;
    int n = __builtin_amdgcn_readfirstlane(blockIdx.x * 4 + (threadIdx.x >> 6));
    if (n >= N_NODES) return;
    const h16* Pr = P + (size_t)n * M;
    float Pk[HROW];
#pragma unroll
    for (int k = 0; k <= HID; k++) Pk[k] = (float)Pr[k * C2 + lane];
    Pk[26] = 0.f; Pk[27] = 0.f;
    int beg = n * SLOTS, end = beg + cnt_src[n];
    int idx = beg;
    for (; idx + 3 < end; idx += 4) {
        int d0 = ebuf[idx], d1 = ebuf[idx + 1], d2 = ebuf[idx + 2], d3 = ebuf[idx + 3];
        float s0 = hdot(h2r + (size_t)idx * HROW, Pk);
        float s1 = hdot(h2r + (size_t)(idx + 1) * HROW, Pk);
        float s2 = hdot(h2r + (size_t)(idx + 2) * HROW, Pk);
        float s3 = hdot(h2r + (size_t)(idx + 3) * HROW, Pk);
        atomicAdd(&agg[d0 * C2 + lane], s0);
        atomicAdd(&agg[d1 * C2 + lane], s1);
        atomicAdd(&agg[d2 * C2 + lane], s2);
        atomicAdd(&agg[d3 * C2 + lane], s3);
    }
    for (; idx < end; idx++) {
        int d0 = ebuf[idx];
        float s0 = hdot(h2r + (size_t)idx * HROW, Pk);
        atomicAdd(&agg[d0 * C2 + lane], s0);
    }
}

// --- K3/K7: node update + BN sums; optional out-zeroing ---
template <int CIN, int COUT>
__global__ void k_node_update(const float* __restrict__ xin, const float* __restrict__ root,
                              const float* __restrict__ bias, const float* __restrict__ agg,
                              const int* __restrict__ degi, float* __restrict__ act,
                              float* __restrict__ s1g, float* __restrict__ s2g,
                              float* zero_out) {
    __shared__ float l1[256], l2[256];
    int tid = threadIdx.x;
    if (zero_out && blockIdx.x == 0 && tid == 0) *zero_out = 0.f;
    int o = tid % COUT;
    float b = bias[o];
    float rcol[CIN];
#pragma unroll
    for (int i = 0; i < CIN; i++) rcol[i] = root[i * COUT + o];
    float acc1 = 0.f, acc2 = 0.f;
    for (int t = blockIdx.x * 256 + tid; t < N_NODES * COUT; t += NU_BLOCKS * 256) {
        int n = t / COUT;
        const float* xr = xin + (size_t)n * CIN;
        float s = b;
#pragma unroll
        for (int i = 0; i < CIN; i++) s += xr[i] * rcol[i];
        s += agg[t] / fmaxf((float)degi[n], 1.0f);
        float a = elu_f(s);
        act[t] = a;
        acc1 += a; acc2 += a * a;
    }
    l1[tid] = acc1; l2[tid] = acc2;
    __syncthreads();
    for (int s = 128; s >= COUT; s >>= 1) {
        if (tid < s) { l1[tid] += l1[tid + s]; l2[tid] += l2[tid + s]; }
        __syncthreads();
    }
    if (tid < COUT) { atomicAdd(&s1g[tid], l1[tid]); atomicAdd(&s2g[tid], l2[tid]); }
}

// --- K4: batchnorm + elu (conv1 only) ---
template <int COUT>
__global__ void k_bn_elu(const float* __restrict__ act, const float* __restrict__ s1g,
                         const float* __restrict__ s2g, const float* __restrict__ gamma,
                         const float* __restrict__ beta, float* __restrict__ out) {
    int t = blockIdx.x * blockDim.x + threadIdx.x;
    if (t >= N_NODES * COUT) return;
    int o = t % COUT;
    float m = s1g[o] * (1.0f / N_NODES);
    float v = s2g[o] * (1.0f / N_NODES) - m * m;
    float x = (act[t] - m) * rsqrtf(v + 1e-5f) * gamma[o] + beta[o];
    out[t] = elu_f(x);
}

// --- K8: BN2+elu fused + fc1 + elu + fc2 + elu + one atomicAdd per block ---
__global__ void k_fc_sum(const float* __restrict__ a2,
                         const float* __restrict__ s1g, const float* __restrict__ s2g,
                         const float* __restrict__ gamma, const float* __restrict__ beta,
                         const float* __restrict__ fc1w, const float* __restrict__ fc1b,
                         const float* __restrict__ fc2w, const float* __restrict__ fc2b,
                         float* __restrict__ out) {
    int tid = threadIdx.x;
    int lane = tid & 63;
    int wave = tid >> 6;
    float m = s1g[lane] * (1.0f / N_NODES);
    float var = s2g[lane] * (1.0f / N_NODES) - m * m;
    float scale = rsqrtf(var + 1e-5f) * gamma[lane];
    float shift = beta[lane] - m * scale;
    float b0 = fc1b[lane], b1 = fc1b[lane + 64];
    float w0 = fc2w[lane], w1 = fc2w[lane + 64];
    float fb = fc2b[0];
    float acc = 0.f;
    for (int n = blockIdx.x * 4 + wave; n < N_NODES; n += FC_BLOCKS * 4) {
        float hval = elu_f(a2[(size_t)n * C2 + lane] * scale + shift);  // coalesced
        float s0 = b0, s1 = b1;
#pragma unroll
        for (int i = 0; i < C2; i++) {
            float hv = __shfl(hval, i);
            s0 += hv * fc1w[i * 128 + lane];
            s1 += hv * fc1w[i * 128 + 64 + lane];
        }
        float v = elu_f(s0) * w0 + elu_f(s1) * w1;
#pragma unroll
        for (int off2 = 32; off2 > 0; off2 >>= 1) v += __shfl_down(v, off2);
        if (lane == 0) acc += elu_f(v + fb);
    }
    __shared__ float lds[4];
    if (lane == 0) lds[wave] = acc;
    __syncthreads();
    if (tid == 0) atomicAdd(out, lds[0] + lds[1] + lds[2] + lds[3]);
}

extern "C" void kernel_launch(void* const* d_in, const int* in_sizes, int n_in,
                              void* d_out, int out_size, void* d_ws, size_t ws_size,
                              hipStream_t stream) {
    const float* x       = (const float*)d_in[0];
    const int*   ei      = (const int*)d_in[1];
    const float* ea      = (const float*)d_in[2];
    const float* nn1_w1  = (const float*)d_in[3];
    const float* nn1_b1  = (const float*)d_in[4];
    const float* nn1_w2  = (const float*)d_in[5];
    const float* nn1_b2  = (const float*)d_in[6];
    const float* c1_root = (const float*)d_in[7];
    const float* c1_bias = (const float*)d_in[8];
    const float* bn1_g   = (const float*)d_in[9];
    const float* bn1_b   = (const float*)d_in[10];
    const float* nn2_w1  = (const float*)d_in[11];
    const float* nn2_b1  = (const float*)d_in[12];
    const float* nn2_w2  = (const float*)d_in[13];
    const float* nn2_b2  = (const float*)d_in[14];
    const float* c2_root = (const float*)d_in[15];
    const float* c2_bias = (const float*)d_in[16];
    const float* bn2_g   = (const float*)d_in[17];
    const float* bn2_b   = (const float*)d_in[18];
    const float* fc1_w   = (const float*)d_in[19];
    const float* fc1_b   = (const float*)d_in[20];
    const float* fc2_w   = (const float*)d_in[21];
    const float* fc2_b   = (const float*)d_in[22];
    float* out = (float*)d_out;

    char* ws = (char*)d_ws;
    size_t off = 0;
    auto alloc = [&](size_t nbytes) -> void* {
        void* q = (void*)(ws + off);
        off += nbytes;
        off = (off + 255) & ~(size_t)255;
        return q;
    };
    // zeroed region first (cnt_src, cnt_dst, agg1, agg2, BN sums)
    int*   cnt_src = (int*)alloc(N_NODES * 4);
    int*   cnt_dst = (int*)alloc(N_NODES * 4);
    float* agg1    = (float*)alloc((size_t)N_NODES * C1 * 4);
    float* agg2    = (float*)alloc((size_t)N_NODES * C2 * 4);
    float* bn1_s1  = (float*)alloc(C1 * 4);
    float* bn1_s2  = (float*)alloc(C1 * 4);
    float* bn2_s1  = (float*)alloc(C2 * 4);
    float* bn2_s2  = (float*)alloc(C2 * 4);
    size_t zero_bytes = off;
    int*   ebuf    = (int*)alloc((size_t)N_NODES * SLOTS * 4);
    h16*   h1r     = (h16*)alloc((size_t)N_NODES * SLOTS * HROW * 2);
    h16*   h2r     = (h16*)alloc((size_t)N_NODES * SLOTS * HROW * 2);
    h16*   P1      = (h16*)alloc((size_t)N_NODES * (HID + 1) * C1 * 2);
    h16*   P2      = (h16*)alloc((size_t)N_NODES * (HID + 1) * C2 * 2);
    float* a1      = (float*)alloc((size_t)N_NODES * C1 * 4);
    float* h1      = (float*)alloc((size_t)N_NODES * C1 * 4);
    float* a2      = (float*)alloc((size_t)N_NODES * C2 * 4);
    (void)ws_size; (void)in_sizes; (void)n_in; (void)out_size;

    hipMemsetAsync(d_ws, 0, zero_bytes, stream);

    constexpr int PRE1_BLOCKS = (((HID + 1) * C1 + 255) / 256) * (N_NODES / 50);  // 800
    constexpr int PRE2_BLOCKS = (((HID + 1) * C2 + 255) / 256) * (N_NODES / 50);  // 1400

    // K1: bucket scatter + edge-MLP hidden + dst degree  ||  precompute P1
    k_scatter_pre1<<<SC_BLOCKS + PRE1_BLOCKS, 256, 0, stream>>>(
        ea, ei, nn1_w1, nn1_b1, nn2_w1, nn2_b1, x, nn1_w2, nn1_b2,
        cnt_src, cnt_dst, ebuf, h1r, h2r, P1);
    // conv1
    k_msg_c1<<<(N_NODES + 3) / 4, 256, 0, stream>>>(P1, cnt_src, ebuf, h1r, agg1);
    k_node_update<FN, C1><<<NU_BLOCKS, 256, 0, stream>>>(x, c1_root, c1_bias, agg1,
                                                         cnt_dst, a1, bn1_s1, bn1_s2, nullptr);
    k_bn_elu<C1><<<(N_NODES * C1) / 256, 256, 0, stream>>>(a1, bn1_s1, bn1_s2, bn1_g, bn1_b, h1);
    // conv2
    k_precompute<C1, C2><<<PRE2_BLOCKS, 256, 0, stream>>>(h1, nn2_w2, nn2_b2, P2);
    k_msg_c2<<<(N_NODES + 3) / 4, 256, 0, stream>>>(P2, cnt_src, ebuf, h2r, agg2);
    k_node_update<C1, C2><<<NU_BLOCKS, 256, 0, stream>>>(h1, c2_root, c2_bias, agg2,
                                                         cnt_dst, a2, bn2_s1, bn2_s2, out);
    // BN2 + fc + global sum
    k_fc_sum<<<FC_BLOCKS, 256, 0, stream>>>(a2, bn2_s1, bn2_s2, bn2_g, bn2_b,
                                            fc1_w, fc1_b, fc2_w, fc2_b, out);
}

// Round 15
// 248.447 us; speedup vs baseline: 1.0186x; 1.0186x over previous
//
#include <hip/hip_runtime.h>
#include <hip/hip_bf16.h>
#include <hip/hip_fp16.h>

#define N_NODES 10000
#define N_EDGES 80000
#define FN 16
#define FE 8
#define HID 25
#define C1 32
#define C2 64
#define NU_BLOCKS 256
#define FC_BLOCKS 640
#define HROW 28   // padded h row in halfs: [25 vals][1.0][0][0] -> 56B, 8B-aligned
#define SLOTS 40  // bucket capacity; Poisson(8) => P(deg>=40) ~ 5e-16
#define SC_BLOCKS ((N_EDGES + 255) / 256)  // 313
#define TN 25     // nodes per precompute block

typedef _Float16 h16;
typedef _Float16 h16x4 __attribute__((ext_vector_type(4)));

__device__ __forceinline__ float elu_f(float x) { return x > 0.f ? x : (expf(x) - 1.f); }

// dot of one padded h row (28 halfs, 7x8B loads; row ptr is wave-uniform/scalar)
__device__ __forceinline__ float hdot(const h16* __restrict__ row, const float* Pk) {
    const h16x4* rv = (const h16x4*)row;
    float s = 0.f;
#pragma unroll
    for (int q = 0; q < 7; q++) {
        h16x4 hv = rv[q];
        s += (float)hv.x * Pk[4 * q] + (float)hv.y * Pk[4 * q + 1] +
             (float)hv.z * Pk[4 * q + 2] + (float)hv.w * Pk[4 * q + 3];
    }
    return s;
}

// --- m-major precompute (fp16 out): P[n,k*COUT+o] = sum_i x[n,i]*w2[k,i,o];
//     row k==HID is the b2 term. One w2 column per thread, reused for TN nodes. ---
template <int CIN, int COUT>
__device__ __forceinline__ void pre_block(const float* __restrict__ xin,
                                          const float* __restrict__ w2,
                                          const float* __restrict__ b2,
                                          h16* __restrict__ P, int u, int tid) {
    constexpr int M = (HID + 1) * COUT;
    constexpr int MB = (M + 255) / 256;
    int mb = u % MB;
    int n0 = (u / MB) * TN;
    int m = mb * 256 + tid;
    if (m >= M) return;
    int k = m / COUT, o = m % COUT;
    float wreg[CIN];
    if (k < HID) {
#pragma unroll
        for (int i = 0; i < CIN; i++) wreg[i] = w2[(size_t)(k * CIN + i) * COUT + o];
    } else {
#pragma unroll
        for (int i = 0; i < CIN; i++) wreg[i] = b2[i * COUT + o];
    }
    for (int n = n0; n < n0 + TN; n++) {
        const float* xr = xin + (size_t)n * CIN;  // wave-uniform -> s_load
        float s = 0.f;
#pragma unroll
        for (int i = 0; i < CIN; i++) s += xr[i] * wreg[i];
        P[(size_t)n * M + m] = (h16)s;
    }
}

// --- K1: blocks [0,SC_BLOCKS): bucket-scatter (packed ebuf) + edge-MLP hidden
//         written EDGE-INDEXED (coalesced 56B/thread stores) + dst degree.
//         blocks beyond: precompute P1. ---
__global__ void k_scatter_pre1(const float* __restrict__ ea, const int* __restrict__ ei,
                               const float* __restrict__ w1a, const float* __restrict__ b1a,
                               const float* __restrict__ w1b, const float* __restrict__ b1b,
                               const float* __restrict__ x, const float* __restrict__ w2a,
                               const float* __restrict__ b2a,
                               int* __restrict__ cnt_src, int* __restrict__ cnt_dst,
                               int* __restrict__ ebuf, h16* __restrict__ h1r,
                               h16* __restrict__ h2r, h16* __restrict__ P1) {
    int tid = threadIdx.x;
    int bid = blockIdx.x;
    if (bid >= SC_BLOCKS) {
        pre_block<FN, C1>(x, w2a, b2a, P1, bid - SC_BLOCKS, tid);
        return;
    }
    __shared__ float sw1a[FE * HID], sw1b[FE * HID], sb1a[HID], sb1b[HID];
    for (int i = tid; i < FE * HID; i += 256) { sw1a[i] = w1a[i]; sw1b[i] = w1b[i]; }
    if (tid < HID) { sb1a[tid] = b1a[tid]; sb1b[tid] = b1b[tid]; }
    __syncthreads();
    int e = bid * 256 + tid;
    if (e >= N_EDGES) return;
    float a[FE];
#pragma unroll
    for (int i = 0; i < FE; i++) a[i] = ea[e * FE + i];
    int src = ei[e], dst = ei[N_EDGES + e];
    int slot = atomicAdd(&cnt_src[src], 1);
    ebuf[src * SLOTS + slot] = (e << 14) | dst;  // e<2^17, dst<2^14
    atomicAdd(&cnt_dst[dst], 1);
    h16 b1buf[HROW], b2buf[HROW];
#pragma unroll
    for (int k = 0; k < HID; k++) {
        float s1 = sb1a[k], s2 = sb1b[k];
#pragma unroll
        for (int i = 0; i < FE; i++) { s1 += a[i] * sw1a[i * HID + k]; s2 += a[i] * sw1b[i * HID + k]; }
        b1buf[k] = (h16)fmaxf(s1, 0.f);
        b2buf[k] = (h16)fmaxf(s2, 0.f);
    }
    // pad: [25]=1 (picks up b2 term in the flat dot), [26]=[27]=0
    b1buf[25] = (h16)1.f; b1buf[26] = (h16)0.f; b1buf[27] = (h16)0.f;
    b2buf[25] = (h16)1.f; b2buf[26] = (h16)0.f; b2buf[27] = (h16)0.f;
    h16x4* h1p = (h16x4*)(h1r + (size_t)e * HROW);  // coalesced: own 56B at e
    h16x4* h2p = (h16x4*)(h2r + (size_t)e * HROW);
#pragma unroll
    for (int q = 0; q < 7; q++) {
        h1p[q] = ((const h16x4*)b1buf)[q];
        h2p[q] = ((const h16x4*)b2buf)[q];
    }
}

// --- K5: conv2 precompute (standalone) ---
template <int CIN, int COUT>
__global__ void k_precompute(const float* __restrict__ xin, const float* __restrict__ w2,
                             const float* __restrict__ b2, h16* __restrict__ P) {
    pre_block<CIN, COUT>(xin, w2, b2, P, blockIdx.x, threadIdx.x);
}

// --- K2: conv1 message. Wave per node; paired edges in half-waves; 4-edge unroll;
//         packed ebuf -> edge-indexed h rows. ---
__global__ void k_msg_c1(const h16* __restrict__ P, const int* __restrict__ cnt_src,
                         const int* __restrict__ ebuf, const h16* __restrict__ h1r,
                         float* __restrict__ agg) {
    constexpr int M = (HID + 1) * C1;
    int lane = threadIdx.x & 63;
    int o = lane & 31;
    int n = __builtin_amdgcn_readfirstlane(blockIdx.x * 4 + (threadIdx.x >> 6));
    if (n >= N_NODES) return;
    const h16* Pr = P + (size_t)n * M;
    float Pk[HROW];
#pragma unroll
    for (int k = 0; k <= HID; k++) Pk[k] = (float)Pr[k * C1 + o];
    Pk[26] = 0.f; Pk[27] = 0.f;
    int beg = n * SLOTS, end = beg + cnt_src[n];
    int idx = beg;
    for (; idx + 3 < end; idx += 4) {
        int p0 = ebuf[idx], p1 = ebuf[idx + 1], p2 = ebuf[idx + 2], p3 = ebuf[idx + 3];
        float s0 = hdot(h1r + (size_t)(p0 >> 14) * HROW, Pk);
        float s1 = hdot(h1r + (size_t)(p1 >> 14) * HROW, Pk);
        float s2 = hdot(h1r + (size_t)(p2 >> 14) * HROW, Pk);
        float s3 = hdot(h1r + (size_t)(p3 >> 14) * HROW, Pk);
        float va = (lane < 32) ? s0 : s1;
        int da = (lane < 32) ? (p0 & 0x3FFF) : (p1 & 0x3FFF);
        atomicAdd(&agg[da * C1 + o], va);
        float vb = (lane < 32) ? s2 : s3;
        int db = (lane < 32) ? (p2 & 0x3FFF) : (p3 & 0x3FFF);
        atomicAdd(&agg[db * C1 + o], vb);
    }
    for (; idx + 1 < end; idx += 2) {
        int p0 = ebuf[idx], p1 = ebuf[idx + 1];
        float s0 = hdot(h1r + (size_t)(p0 >> 14) * HROW, Pk);
        float s1 = hdot(h1r + (size_t)(p1 >> 14) * HROW, Pk);
        float va = (lane < 32) ? s0 : s1;
        int da = (lane < 32) ? (p0 & 0x3FFF) : (p1 & 0x3FFF);
        atomicAdd(&agg[da * C1 + o], va);
    }
    if (idx < end) {
        int p0 = ebuf[idx];
        float s0 = hdot(h1r + (size_t)(p0 >> 14) * HROW, Pk);
        if (lane < 32) atomicAdd(&agg[(p0 & 0x3FFF) * C1 + o], s0);
    }
}

// --- K6: conv2 message. Wave per node; lane = channel; 4-edge unroll; packed ebuf. ---
__global__ void k_msg_c2(const h16* __restrict__ P, const int* __restrict__ cnt_src,
                         const int* __restrict__ ebuf, const h16* __restrict__ h2r,
                         float* __restrict__ agg) {
    constexpr int M = (HID + 1) * C2;
    int lane = threadIdx.x & 63;
    int n = __builtin_amdgcn_readfirstlane(blockIdx.x * 4 + (threadIdx.x >> 6));
    if (n >= N_NODES) return;
    const h16* Pr = P + (size_t)n * M;
    float Pk[HROW];
#pragma unroll
    for (int k = 0; k <= HID; k++) Pk[k] = (float)Pr[k * C2 + lane];
    Pk[26] = 0.f; Pk[27] = 0.f;
    int beg = n * SLOTS, end = beg + cnt_src[n];
    int idx = beg;
    for (; idx + 3 < end; idx += 4) {
        int p0 = ebuf[idx], p1 = ebuf[idx + 1], p2 = ebuf[idx + 2], p3 = ebuf[idx + 3];
        float s0 = hdot(h2r + (size_t)(p0 >> 14) * HROW, Pk);
        float s1 = hdot(h2r + (size_t)(p1 >> 14) * HROW, Pk);
        float s2 = hdot(h2r + (size_t)(p2 >> 14) * HROW, Pk);
        float s3 = hdot(h2r + (size_t)(p3 >> 14) * HROW, Pk);
        atomicAdd(&agg[(p0 & 0x3FFF) * C2 + lane], s0);
        atomicAdd(&agg[(p1 & 0x3FFF) * C2 + lane], s1);
        atomicAdd(&agg[(p2 & 0x3FFF) * C2 + lane], s2);
        atomicAdd(&agg[(p3 & 0x3FFF) * C2 + lane], s3);
    }
    for (; idx < end; idx++) {
        int p0 = ebuf[idx];
        float s0 = hdot(h2r + (size_t)(p0 >> 14) * HROW, Pk);
        atomicAdd(&agg[(p0 & 0x3FFF) * C2 + lane], s0);
    }
}

// --- K3/K7: node update + BN sums; optional out-zeroing ---
template <int CIN, int COUT>
__global__ void k_node_update(const float* __restrict__ xin, const float* __restrict__ root,
                              const float* __restrict__ bias, const float* __restrict__ agg,
                              const int* __restrict__ degi, float* __restrict__ act,
                              float* __restrict__ s1g, float* __restrict__ s2g,
                              float* zero_out) {
    __shared__ float l1[256], l2[256];
    int tid = threadIdx.x;
    if (zero_out && blockIdx.x == 0 && tid == 0) *zero_out = 0.f;
    int o = tid % COUT;
    float b = bias[o];
    float rcol[CIN];
#pragma unroll
    for (int i = 0; i < CIN; i++) rcol[i] = root[i * COUT + o];
    float acc1 = 0.f, acc2 = 0.f;
    for (int t = blockIdx.x * 256 + tid; t < N_NODES * COUT; t += NU_BLOCKS * 256) {
        int n = t / COUT;
        const float* xr = xin + (size_t)n * CIN;
        float s = b;
#pragma unroll
        for (int i = 0; i < CIN; i++) s += xr[i] * rcol[i];
        s += agg[t] / fmaxf((float)degi[n], 1.0f);
        float a = elu_f(s);
        act[t] = a;
        acc1 += a; acc2 += a * a;
    }
    l1[tid] = acc1; l2[tid] = acc2;
    __syncthreads();
    for (int s = 128; s >= COUT; s >>= 1) {
        if (tid < s) { l1[tid] += l1[tid + s]; l2[tid] += l2[tid + s]; }
        __syncthreads();
    }
    if (tid < COUT) { atomicAdd(&s1g[tid], l1[tid]); atomicAdd(&s2g[tid], l2[tid]); }
}

// --- K4: batchnorm + elu (conv1 only) ---
template <int COUT>
__global__ void k_bn_elu(const float* __restrict__ act, const float* __restrict__ s1g,
                         const float* __restrict__ s2g, const float* __restrict__ gamma,
                         const float* __restrict__ beta, float* __restrict__ out) {
    int t = blockIdx.x * blockDim.x + threadIdx.x;
    if (t >= N_NODES * COUT) return;
    int o = t % COUT;
    float m = s1g[o] * (1.0f / N_NODES);
    float v = s2g[o] * (1.0f / N_NODES) - m * m;
    float x = (act[t] - m) * rsqrtf(v + 1e-5f) * gamma[o] + beta[o];
    out[t] = elu_f(x);
}

// --- K8: BN2+elu fused + fc1 + elu + fc2 + elu + one atomicAdd per block ---
__global__ void k_fc_sum(const float* __restrict__ a2,
                         const float* __restrict__ s1g, const float* __restrict__ s2g,
                         const float* __restrict__ gamma, const float* __restrict__ beta,
                         const float* __restrict__ fc1w, const float* __restrict__ fc1b,
                         const float* __restrict__ fc2w, const float* __restrict__ fc2b,
                         float* __restrict__ out) {
    int tid = threadIdx.x;
    int lane = tid & 63;
    int wave = tid >> 6;
    float m = s1g[lane] * (1.0f / N_NODES);
    float var = s2g[lane] * (1.0f / N_NODES) - m * m;
    float scale = rsqrtf(var + 1e-5f) * gamma[lane];
    float shift = beta[lane] - m * scale;
    float b0 = fc1b[lane], b1 = fc1b[lane + 64];
    float w0 = fc2w[lane], w1 = fc2w[lane + 64];
    float fb = fc2b[0];
    float acc = 0.f;
    for (int n = blockIdx.x * 4 + wave; n < N_NODES; n += FC_BLOCKS * 4) {
        float hval = elu_f(a2[(size_t)n * C2 + lane] * scale + shift);  // coalesced
        float s0 = b0, s1 = b1;
#pragma unroll
        for (int i = 0; i < C2; i++) {
            float hv = __shfl(hval, i);
            s0 += hv * fc1w[i * 128 + lane];
            s1 += hv * fc1w[i * 128 + 64 + lane];
        }
        float v = elu_f(s0) * w0 + elu_f(s1) * w1;
#pragma unroll
        for (int off2 = 32; off2 > 0; off2 >>= 1) v += __shfl_down(v, off2);
        if (lane == 0) acc += elu_f(v + fb);
    }
    __shared__ float lds[4];
    if (lane == 0) lds[wave] = acc;
    __syncthreads();
    if (tid == 0) atomicAdd(out, lds[0] + lds[1] + lds[2] + lds[3]);
}

extern "C" void kernel_launch(void* const* d_in, const int* in_sizes, int n_in,
                              void* d_out, int out_size, void* d_ws, size_t ws_size,
                              hipStream_t stream) {
    const float* x       = (const float*)d_in[0];
    const int*   ei      = (const int*)d_in[1];
    const float* ea      = (const float*)d_in[2];
    const float* nn1_w1  = (const float*)d_in[3];
    const float* nn1_b1  = (const float*)d_in[4];
    const float* nn1_w2  = (const float*)d_in[5];
    const float* nn1_b2  = (const float*)d_in[6];
    const float* c1_root = (const float*)d_in[7];
    const float* c1_bias = (const float*)d_in[8];
    const float* bn1_g   = (const float*)d_in[9];
    const float* bn1_b   = (const float*)d_in[10];
    const float* nn2_w1  = (const float*)d_in[11];
    const float* nn2_b1  = (const float*)d_in[12];
    const float* nn2_w2  = (const float*)d_in[13];
    const float* nn2_b2  = (const float*)d_in[14];
    const float* c2_root = (const float*)d_in[15];
    const float* c2_bias = (const float*)d_in[16];
    const float* bn2_g   = (const float*)d_in[17];
    const float* bn2_b   = (const float*)d_in[18];
    const float* fc1_w   = (const float*)d_in[19];
    const float* fc1_b   = (const float*)d_in[20];
    const float* fc2_w   = (const float*)d_in[21];
    const float* fc2_b   = (const float*)d_in[22];
    float* out = (float*)d_out;

    char* ws = (char*)d_ws;
    size_t off = 0;
    auto alloc = [&](size_t nbytes) -> void* {
        void* q = (void*)(ws + off);
        off += nbytes;
        off = (off + 255) & ~(size_t)255;
        return q;
    };
    // zeroed region first (cnt_src, cnt_dst, agg1, agg2, BN sums)
    int*   cnt_src = (int*)alloc(N_NODES * 4);
    int*   cnt_dst = (int*)alloc(N_NODES * 4);
    float* agg1    = (float*)alloc((size_t)N_NODES * C1 * 4);
    float* agg2    = (float*)alloc((size_t)N_NODES * C2 * 4);
    float* bn1_s1  = (float*)alloc(C1 * 4);
    float* bn1_s2  = (float*)alloc(C1 * 4);
    float* bn2_s1  = (float*)alloc(C2 * 4);
    float* bn2_s2  = (float*)alloc(C2 * 4);
    size_t zero_bytes = off;
    int*   ebuf    = (int*)alloc((size_t)N_NODES * SLOTS * 4);
    h16*   h1r     = (h16*)alloc((size_t)N_EDGES * HROW * 2);
    h16*   h2r     = (h16*)alloc((size_t)N_EDGES * HROW * 2);
    h16*   P1      = (h16*)alloc((size_t)N_NODES * (HID + 1) * C1 * 2);
    h16*   P2      = (h16*)alloc((size_t)N_NODES * (HID + 1) * C2 * 2);
    float* a1      = (float*)alloc((size_t)N_NODES * C1 * 4);
    float* h1      = (float*)alloc((size_t)N_NODES * C1 * 4);
    float* a2      = (float*)alloc((size_t)N_NODES * C2 * 4);
    (void)ws_size; (void)in_sizes; (void)n_in; (void)out_size;

    hipMemsetAsync(d_ws, 0, zero_bytes, stream);

    constexpr int PRE1_BLOCKS = (((HID + 1) * C1 + 255) / 256) * (N_NODES / TN);  // 1600
    constexpr int PRE2_BLOCKS = (((HID + 1) * C2 + 255) / 256) * (N_NODES / TN);  // 2800

    // K1: bucket scatter + edge-MLP hidden + dst degree  ||  precompute P1
    k_scatter_pre1<<<SC_BLOCKS + PRE1_BLOCKS, 256, 0, stream>>>(
        ea, ei, nn1_w1, nn1_b1, nn2_w1, nn2_b1, x, nn1_w2, nn1_b2,
        cnt_src, cnt_dst, ebuf, h1r, h2r, P1);
    // conv1
    k_msg_c1<<<(N_NODES + 3) / 4, 256, 0, stream>>>(P1, cnt_src, ebuf, h1r, agg1);
    k_node_update<FN, C1><<<NU_BLOCKS, 256, 0, stream>>>(x, c1_root, c1_bias, agg1,
                                                         cnt_dst, a1, bn1_s1, bn1_s2, nullptr);
    k_bn_elu<C1><<<(N_NODES * C1) / 256, 256, 0, stream>>>(a1, bn1_s1, bn1_s2, bn1_g, bn1_b, h1);
    // conv2
    k_precompute<C1, C2><<<PRE2_BLOCKS, 256, 0, stream>>>(h1, nn2_w2, nn2_b2, P2);
    k_msg_c2<<<(N_NODES + 3) / 4, 256, 0, stream>>>(P2, cnt_src, ebuf, h2r, agg2);
    k_node_update<C1, C2><<<NU_BLOCKS, 256, 0, stream>>>(h1, c2_root, c2_bias, agg2,
                                                         cnt_dst, a2, bn2_s1, bn2_s2, out);
    // BN2 + fc + global sum
    k_fc_sum<<<FC_BLOCKS, 256, 0, stream>>>(a2, bn2_s1, bn2_s2, bn2_g, bn2_b,
                                            fc1_w, fc1_b, fc2_w, fc2_b, out);
}